// Round 13
// baseline (101.875 us; speedup 1.0000x reference)
//
#include <hip/hip_runtime.h>
#include <stdint.h>

typedef short bf16x8 __attribute__((ext_vector_type(8)));
typedef unsigned short u16x8 __attribute__((ext_vector_type(8)));
typedef float f32x4 __attribute__((ext_vector_type(4)));
typedef float f32x8 __attribute__((ext_vector_type(8)));

constexpr int BT_TOT = 768;   // B*T
constexpr int M_N    = 512;   // nodes
constexpr int DD     = 64;    // Din = Dout
constexpr int WROW   = 72;    // W' row stride in route_mm

constexpr size_t ADJ_FRAG_B = (size_t)M_N * M_N * 2;          // 512 KB
constexpr size_t XTF_B      = (size_t)BT_TOT * M_N * DD * 2;  // 48 MB
constexpr size_t HWS_B      = (size_t)BT_TOT * M_N * DD * 2;  // 48 MB (H2 layout)

__device__ __forceinline__ unsigned short f2bf(float f) {
  unsigned u = __builtin_bit_cast(unsigned, f);
  u += 0x7fffu + ((u >> 16) & 1u);          // RNE
  return (unsigned short)(u >> 16);
}
__device__ __forceinline__ unsigned pk2(float a, float b) {
  return (unsigned)f2bf(a) | ((unsigned)f2bf(b) << 16);
}
__device__ __forceinline__ void gload16(const unsigned short* g, char* l) {
  __builtin_amdgcn_global_load_lds(
      (const __attribute__((address_space(1))) unsigned int*)g,
      (__attribute__((address_space(3))) unsigned int*)l, 16, 0, 0);
}

// ---- adj f32 -> bf16 MFMA-fragment layout (verified r11) ----
__global__ __launch_bounds__(256)
void prep_adj_frag(const float* __restrict__ adjg, unsigned short* __restrict__ wsadj) {
  int t  = blockIdx.x * 256 + threadIdx.x;   // granule id = m*64 + ko
  int m  = t >> 6, ko = t & 63;
  f32x8 a = *(const f32x8*)(adjg + (size_t)m * M_N + ko * 8);
  u16x8 r;
  #pragma unroll
  for (int j = 0; j < 8; ++j) r[j] = f2bf(a[j]);
  size_t g = (size_t)((m >> 4) * 16 + (ko >> 2)) * 64 + (ko & 3) * 16 + (m & 15);
  *(u16x8*)(wsadj + g * 8) = r;
}

// ---- x f32 [bt][n][d] -> xtf bf16 fragment layout (verified r11) ----
__global__ __launch_bounds__(256)
void prep_x_fast(const float* __restrict__ xg, unsigned short* __restrict__ xtf) {
  const int wid = blockIdx.x;          // 0..3071
  const int bt  = wid >> 2, q = wid & 3;
  const int tid = threadIdx.x, lane = tid & 63, w = tid >> 6;
  const int gg  = lane >> 4, c4 = lane & 15;

  const float* xb = xg + (size_t)bt * (M_N * DD);
  unsigned short* xo = xtf + (size_t)bt * 32768;

  #pragma unroll
  for (int cc = 0; cc < 2; ++cc) {
    const int c = q * 2 + cc;
    unsigned r0[4], r1[4];
    #pragma unroll
    for (int s2 = 0; s2 < 2; ++s2) {
      #pragma unroll
      for (int sp = 0; sp < 2; ++sp) {
        const int n = c*64 + w*16 + (s2*2 + sp)*4 + gg;
        f32x4 xv = *(const f32x4*)(xb + (size_t)n * DD + c4*4);
        unsigned u0 = pk2(xv.x, xv.y), u1 = pk2(xv.z, xv.w);
        unsigned t0 = __shfl_xor(u0, 32), t1 = __shfl_xor(u1, 32);
        unsigned v0 = (gg & 2) ? t1 : u0, v1 = (gg & 2) ? u1 : t0;
        unsigned s0 = __shfl_xor(v0, 16), s1 = __shfl_xor(v1, 16);
        unsigned F0 = (gg & 1) ? ((s0 >> 16) | (v0 & 0xFFFF0000u))
                               : ((v0 & 0xFFFFu) | (s0 << 16));
        unsigned F1 = (gg & 1) ? ((s1 >> 16) | (v1 & 0xFFFF0000u))
                               : ((v1 & 0xFFFFu) | (s1 << 16));
        if (s2 == 0) { r0[sp*2] = F0; r0[sp*2+1] = F1; }
        else         { r1[sp*2] = F0; r1[sp*2+1] = F1; }
      }
    }
    const int d = c4*4 + gg, dt = d >> 4, l15p = d & 15;
    #pragma unroll
    for (int h = 0; h < 2; ++h) {
      const int o  = w*2 + h;
      const int kl = c*2 + (o >> 2), ggp = o & 3;
      uint4 val;
      if (h == 0) { val.x=r0[0]; val.y=r0[1]; val.z=r0[2]; val.w=r0[3]; }
      else        { val.x=r1[0]; val.y=r1[1]; val.z=r1[2]; val.w=r1[3]; }
      *(uint4*)(xo + ((size_t)(kl*4 + dt)*64 + ggp*16 + l15p) * 8) = val;
    }
  }
}

// ---- gconv r13: xtf LDS-shared (global_load_lds, linear), afr direct L2 ----
// WG = 256 thr / 4 waves = 2 bt x 128 m. Chunk = kl-pair (K=64): 16KB staged
// once per WG (was 4x wave-redundant from L2). afr issued BEFORE stage so its
// vmcnt wait doesn't drain the in-flight stage (FIFO). 1 barrier per chunk.
// H stored as H2[(m*2+ks)][bt][64B] via verified LDS repack.
__global__ __launch_bounds__(256, 3)
void gconv_r13(const unsigned short* __restrict__ adjF,
               const unsigned short* __restrict__ xtf,
               unsigned short* __restrict__ h2) {
  __shared__ __align__(16) char lds[36864];   // 2x16KB stage bufs; 36.9KB epilogue

  const int wid  = blockIdx.x;        // 0..1535, bijective XCD swizzle (verified)
  const int xcd  = wid & 7, slot = wid >> 3;
  const int mb   = slot & 3;
  const int bt0  = ((slot >> 2) * 8 + xcd) * 2;

  const int tid  = threadIdx.x, lane = tid & 63, wv = tid >> 6;
  const int l15  = lane & 15, gg = lane >> 4;

  auto stage = [&](int c) {           // 4 x global_load_lds(16B) per thread
    char* buf = lds + (c & 1) * 16384;
    #pragma unroll
    for (int j = 0; j < 4; ++j) {
      const int su = j*4 + wv;        // wave-uniform slot group = (bb*2+kk)*4+dt
      const int bb = su >> 3, kk = (su >> 2) & 1, dt = su & 3;
      const unsigned short* src = xtf + (size_t)(bt0 + bb) * 32768
                                + ((size_t)((2*c + kk)*4 + dt)*64 + lane) * 8;
      gload16(src, buf + su*1024 + lane*16);
    }
  };

  f32x4 acc[2][2][4];                 // [bb][mt][dt]
  #pragma unroll
  for (int bb = 0; bb < 2; ++bb)
    #pragma unroll
    for (int mt = 0; mt < 2; ++mt)
      #pragma unroll
      for (int dt = 0; dt < 4; ++dt) acc[bb][mt][dt] = f32x4{0.f,0.f,0.f,0.f};

  stage(0);
  __syncthreads();                    // vmcnt(0) drain: buf0 ready

  #pragma unroll 1
  for (int c = 0; c < 8; ++c) {
    bf16x8 afr[2][2];                 // [kk][mt] — issued FIRST (older than stage)
    #pragma unroll
    for (int kk = 0; kk < 2; ++kk)
      #pragma unroll
      for (int mt = 0; mt < 2; ++mt)
        afr[kk][mt] = __builtin_bit_cast(bf16x8, *(const u16x8*)(adjF
            + ((size_t)((mb*8 + wv*2 + mt)*16 + (2*c + kk))*64 + lane) * 8));
    if (c < 7) stage(c + 1);          // stays in flight across the MFMA phase

    const char* buf = lds + (c & 1) * 16384;
    #pragma unroll
    for (int kk = 0; kk < 2; ++kk) {
      bf16x8 bfx[2][4];
      #pragma unroll
      for (int bb = 0; bb < 2; ++bb)
        #pragma unroll
        for (int dt = 0; dt < 4; ++dt)
          bfx[bb][dt] = __builtin_bit_cast(bf16x8,
              *(const u16x8*)(buf + ((bb*2 + kk)*4 + dt)*1024 + lane*16));
      #pragma unroll
      for (int bb = 0; bb < 2; ++bb)
        #pragma unroll
        for (int mt = 0; mt < 2; ++mt)
          #pragma unroll
          for (int dt = 0; dt < 4; ++dt)
            acc[bb][mt][dt] = __builtin_amdgcn_mfma_f32_16x16x32_bf16(
                afr[kk][mt], bfx[bb][dt], acc[bb][mt][dt], 0,0,0);
    }
    __syncthreads();                  // next buf ready; readers of this buf done
  }

  // epilogue: acc -> LDS rows [bb*128+mloc][72 shorts] (verified) -> H2 stores
  unsigned short* hl = (unsigned short*)lds;
  #pragma unroll
  for (int bb = 0; bb < 2; ++bb)
    #pragma unroll
    for (int mt = 0; mt < 2; ++mt)
      #pragma unroll
      for (int dt = 0; dt < 4; ++dt)
        #pragma unroll
        for (int r = 0; r < 4; ++r) {
          const int rl = bb*128 + wv*32 + mt*16 + gg*4 + r;  // C row = gg*4+r
          hl[rl*72 + dt*16 + l15] = f2bf(acc[bb][mt][dt][r]);
        }
  __syncthreads();
  #pragma unroll
  for (int i = 0; i < 8; ++i) {
    const int g  = tid + i*256;       // 2048 granules of 16B
    const int rl = g >> 3, qq = g & 7;
    u16x8 v = *(const u16x8*)(hl + rl*72 + qq*8);
    const int bb = rl >> 7, mloc = rl & 127;
    const int m  = mb*128 + mloc, ks = qq >> 2, o = qq & 3;
    *(u16x8*)((char*)h2 + (((size_t)m*2 + ks)*768 + bt0 + bb)*64 + o*16) = v;
  }
}

// ================= FALLBACK (r10/r12 verified) =================

__global__ __launch_bounds__(256)
void prep_adj(const float* __restrict__ adjg, unsigned short* __restrict__ wsadj) {
  int i = (blockIdx.x * 256 + threadIdx.x) * 8;
  f32x8 a = *(const f32x8*)(adjg + i);
  u16x8 r;
  #pragma unroll
  for (int j = 0; j < 8; ++j) r[j] = f2bf(a[j]);
  *(u16x8*)(wsadj + i) = r;
}

__global__ __launch_bounds__(256, 4)
void prep_x_fb(const float* __restrict__ xg, char* __restrict__ xout) {
  __shared__ __align__(16) char lds[2][8192];
  const int wid  = blockIdx.x;
  const int bt   = wid >> 1, half = wid & 1;
  const int tid  = threadIdx.x, lane = tid & 63, wv = tid >> 6;
  const int gg   = lane >> 4, c4 = lane & 15;
  const float* xb = xg + (size_t)bt * (M_N * DD);
  f32x4 xv[4];
  auto load_c = [&](int c) {
    #pragma unroll
    for (int s = 0; s < 4; ++s)
      xv[s] = *(const f32x4*)(xb + (size_t)(c*64 + s*16 + wv*4 + gg) * DD + c4*4);
  };
  load_c(half*4);
  #pragma unroll
  for (int cc = 0; cc < 4; ++cc) {
    const int c = half*4 + cc;
    char* xt = &lds[cc & 1][0];
    { const int d = c4*4 + gg, g3d = (d & 7) ^ ((d >> 3) & 7);
      #pragma unroll
      for (int s = 0; s < 4; ++s) {
        const int n4 = s*4 + wv;
        unsigned u0 = pk2(xv[s].x, xv[s].y), u1 = pk2(xv[s].z, xv[s].w);
        unsigned t0 = __shfl_xor(u0, 32), t1 = __shfl_xor(u1, 32);
        unsigned v0 = (gg & 2) ? t1 : u0, v1 = (gg & 2) ? u1 : t0;
        unsigned s0 = __shfl_xor(v0, 16), s1 = __shfl_xor(v1, 16);
        unsigned F0 = (gg & 1) ? ((s0 >> 16) | (v0 & 0xFFFF0000u))
                               : ((v0 & 0xFFFFu) | (s0 << 16));
        unsigned F1 = (gg & 1) ? ((s1 >> 16) | (v1 & 0xFFFF0000u))
                               : ((v1 & 0xFFFFu) | (s1 << 16));
        uint2 o2; o2.x = F0; o2.y = F1;
        *(uint2*)(xt + d*128 + (((n4 >> 1) ^ g3d) * 16) + (n4 & 1)*8) = o2;
      }
    }
    if (cc < 3) load_c(c + 1);
    __syncthreads();
    #pragma unroll
    for (int h = 0; h < 2; ++h) {
      const int g = tid + h*256, d = g >> 3, o = g & 7;
      const int g3d = (d & 7) ^ ((d >> 3) & 7);
      u16x8 val = *(const u16x8*)(xt + d*128 + ((o ^ g3d) * 16));
      *(u16x8*)(xout + ((size_t)(bt*512 + 8*d + c)) * 256 + 128 + o*16) = val;
    }
  }
}

template<bool WS>
__global__ __launch_bounds__(256, 3)
void gconv_fb(const float* __restrict__ adjf,
              const unsigned short* __restrict__ adjb,
              char* __restrict__ dio) {
  const int wid  = blockIdx.x;
  const int xcd  = wid & 7, slot = wid >> 3;
  const int mb   = slot & 3;
  const int bt0  = ((slot >> 2) * 8 + xcd) * 2;
  const int tid  = threadIdx.x, lane = tid & 63, wv = tid >> 6;
  const int l15  = lane & 15, gg = lane >> 4;
  const int mrow = mb*128 + wv*32;
  f32x4 acc[2][2][4];
  #pragma unroll
  for (int bb = 0; bb < 2; ++bb)
    #pragma unroll
    for (int mt = 0; mt < 2; ++mt)
      #pragma unroll
      for (int dt = 0; dt < 4; ++dt) acc[bb][mt][dt] = f32x4{0.f,0.f,0.f,0.f};
  #pragma unroll 4
  for (int kl = 0; kl < 16; ++kl) {
    bf16x8 afr[2];
    #pragma unroll
    for (int mt = 0; mt < 2; ++mt) {
      const int m = mrow + mt*16 + l15;
      if (WS) {
        afr[mt] = __builtin_bit_cast(bf16x8,
            *(const u16x8*)(adjb + (size_t)m*M_N + kl*32 + gg*8));
      } else {
        f32x8 a = *(const f32x8*)(adjf + (size_t)m*M_N + kl*32 + gg*8);
        u16x8 r;
        #pragma unroll
        for (int j = 0; j < 8; ++j) r[j] = f2bf(a[j]);
        afr[mt] = __builtin_bit_cast(bf16x8, r);
      }
    }
    bf16x8 bfx[2][4];
    #pragma unroll
    for (int bb = 0; bb < 2; ++bb)
      #pragma unroll
      for (int dt = 0; dt < 4; ++dt) {
        const int d = dt*16 + l15;
        bfx[bb][dt] = __builtin_bit_cast(bf16x8, *(const u16x8*)(dio
            + ((size_t)((bt0+bb)*512 + 8*d + (kl >> 1))) * 256
            + 128 + (kl & 1)*64 + gg*16));
      }
    #pragma unroll
    for (int bb = 0; bb < 2; ++bb)
      #pragma unroll
      for (int mt = 0; mt < 2; ++mt)
        #pragma unroll
        for (int dt = 0; dt < 4; ++dt)
          acc[bb][mt][dt] = __builtin_amdgcn_mfma_f32_16x16x32_bf16(
              afr[mt], bfx[bb][dt], acc[bb][mt][dt], 0,0,0);
  }
  #pragma unroll
  for (int bb = 0; bb < 2; ++bb)
    #pragma unroll
    for (int mt = 0; mt < 2; ++mt)
      #pragma unroll
      for (int dt = 0; dt < 4; ++dt)
        #pragma unroll
        for (int r = 0; r < 4; ++r) {
          const int m = mrow + mt*16 + gg*4 + r, d = dt*16 + l15;
          *(unsigned short*)(dio + ((size_t)(bt0+bb)*M_N + m)*256 + 2*d)
              = f2bf(acc[bb][mt][dt][r]);
        }
}

// ---------------- route_mm: H2L = fragment-major H (contiguous 1KB reads) ----------------
template<bool H2L>
__global__ __launch_bounds__(256, 4)
void route_mm(const char* __restrict__ hin,
              const float* __restrict__ wgt,
              const float* __restrict__ bias,
              float* __restrict__ outg) {
  __shared__ unsigned short wb[128 * WROW];
  const int m0    = blockIdx.x * 2;
  const int btblk = blockIdx.y * 64;
  const int tid   = threadIdx.x, lane = tid & 63, wv = tid >> 6;
  const int l15   = lane & 15, gg = lane >> 4;
  const int dp    = tid & 31, lo = tid >> 5;
  { const float* q = wgt + ((size_t)m0*64 + dp*2)*64 + lo*8;
    f32x8 w0 = *(const f32x8*)q;          f32x8 w1 = *(const f32x8*)(q+64);
    f32x8 w2 = *(const f32x8*)(q+4096);   f32x8 w3 = *(const f32x8*)(q+4160);
    #pragma unroll
    for (int e = 0; e < 8; ++e) {
      int lrow = lo*8 + e;
      *(unsigned*)(wb + lrow*WROW + dp*2)        = pk2(w0[e], w1[e]);
      *(unsigned*)(wb + (64 + lrow)*WROW + dp*2) = pk2(w2[e], w3[e]);
    }
  }
  __syncthreads();
  const int btw0 = btblk + wv*16;
  #pragma unroll
  for (int mm = 0; mm < 2; ++mm) {
    const int m = m0 + mm;
    bf16x8 afr[2];
    #pragma unroll
    for (int ks = 0; ks < 2; ++ks) {
      const char* hp = H2L
        ? hin + (((size_t)m*2 + ks)*768 + btw0 + l15)*64 + gg*16
        : hin + ((size_t)(btw0 + l15)*M_N + m)*256 + ks*64 + gg*16;
      afr[ks] = __builtin_bit_cast(bf16x8, *(const u16x8*)hp);
    }
    f32x4 acc[4];
    #pragma unroll
    for (int lt = 0; lt < 4; ++lt) acc[lt] = f32x4{0.f,0.f,0.f,0.f};
    #pragma unroll
    for (int lt = 0; lt < 4; ++lt)
      #pragma unroll
      for (int ks = 0; ks < 2; ++ks) {
        bf16x8 bfr = __builtin_bit_cast(bf16x8,
            *(const u16x8*)(wb + (mm*64 + lt*16 + l15)*WROW + ks*32 + gg*8));
        acc[lt] = __builtin_amdgcn_mfma_f32_16x16x32_bf16(afr[ks], bfr, acc[lt], 0,0,0);
      }
    #pragma unroll
    for (int lt = 0; lt < 4; ++lt) {
      float bv = bias[m*64 + lt*16 + l15];
      #pragma unroll
      for (int r = 0; r < 4; ++r) {
        size_t row = (size_t)(btw0 + gg*4 + r)*M_N + m;
        outg[row*64 + lt*16 + l15] = acc[lt][r] + bv;
      }
    }
  }
}

extern "C" void kernel_launch(void* const* d_in, const int* in_sizes, int n_in,
                              void* d_out, int out_size, void* d_ws, size_t ws_size,
                              hipStream_t stream) {
  const float* xg   = (const float*)d_in[0];
  const float* adjg = (const float*)d_in[1];
  const float* wgt  = (const float*)d_in[2];
  const float* bg   = (const float*)d_in[3];

  if (ws_size >= ADJ_FRAG_B + XTF_B + HWS_B) {
    unsigned short* adjF = (unsigned short*)d_ws;
    unsigned short* xtf  = (unsigned short*)((char*)d_ws + ADJ_FRAG_B);
    unsigned short* h2   = (unsigned short*)((char*)d_ws + ADJ_FRAG_B + XTF_B);
    prep_adj_frag<<<dim3(128), dim3(256), 0, stream>>>(adjg, adjF);
    prep_x_fast<<<dim3(BT_TOT * 4), dim3(256), 0, stream>>>(xg, xtf);
    gconv_r13<<<dim3(1536), dim3(256), 0, stream>>>(adjF, xtf, h2);
    route_mm<true><<<dim3(M_N/2, BT_TOT/64), dim3(256), 0, stream>>>(
        (const char*)h2, wgt, bg, (float*)d_out);
  } else {
    prep_x_fb<<<dim3(BT_TOT * 2), dim3(256), 0, stream>>>(xg, (char*)d_out);
    if (ws_size >= ADJ_FRAG_B) {
      unsigned short* wsadj = (unsigned short*)d_ws;
      prep_adj<<<dim3(M_N * M_N / (256 * 8)), dim3(256), 0, stream>>>(adjg, wsadj);
      gconv_fb<true><<<dim3(1536), dim3(256), 0, stream>>>(adjg, wsadj, (char*)d_out);
    } else {
      gconv_fb<false><<<dim3(1536), dim3(256), 0, stream>>>(adjg, nullptr, (char*)d_out);
    }
    route_mm<false><<<dim3(M_N/2, BT_TOT/64), dim3(256), 0, stream>>>(
        (const char*)d_out, wgt, bg, (float*)d_out);
  }
}